// Round 5
// baseline (796.557 us; speedup 1.0000x reference)
//
#include <hip/hip_runtime.h>
#include <hip/hip_fp16.h>
#include <stdint.h>

#define IN_F   4096
#define OUT_F  4096
#define M_ROWS 8192
#define BM 256
#define BN 256
#define BK 32

typedef _Float16 v8h __attribute__((ext_vector_type(8)));
typedef float    v4f __attribute__((ext_vector_type(4)));

// ---------------- Kernel 1: fused dequant (3-bit -> f16 w) + cast (x f32 -> f16) ----------
// blocks [0, 2048): dequant 524288 groups. blocks [2048, 18432): cast 33.5M floats.
__global__ void prep_kernel(const int* __restrict__ q,
                            const float* __restrict__ norm,
                            _Float16* __restrict__ w,
                            const float* __restrict__ x,
                            _Float16* __restrict__ xo) {
    int bid = blockIdx.x;
    if (bid < 2048) {
        int g = bid * 256 + threadIdx.x;             // 524288 groups
        const int4* p = (const int4*)(q + (size_t)g * 12);  // 48 B (int-widened bytes)
        int4 q0 = p[0], q1 = p[1], q2 = p[2];
        uint32_t b[12] = {(uint32_t)q0.x, (uint32_t)q0.y, (uint32_t)q0.z, (uint32_t)q0.w,
                          (uint32_t)q1.x, (uint32_t)q1.y, (uint32_t)q1.z, (uint32_t)q1.w,
                          (uint32_t)q2.x, (uint32_t)q2.y, (uint32_t)q2.z, (uint32_t)q2.w};
        uint64_t lo = 0, hi = 0;
#pragma unroll
        for (int i = 0; i < 8; ++i) lo |= (uint64_t)(b[i] & 0xff) << (8 * i);
#pragma unroll
        for (int i = 0; i < 8; ++i) hi |= (uint64_t)(b[4 + i] & 0xff) << (8 * i);
        float nrm = norm[g];
        float scale = nrm * (2.0f / 7.0f);
        v8h out[4];
#pragma unroll
        for (int i = 0; i < 32; ++i) {
            int p3 = 3 * i;
            uint32_t qv = (i <= 20) ? (uint32_t)((lo >> p3) & 7)
                                    : (uint32_t)((hi >> (p3 - 32)) & 7);
            out[i >> 3][i & 7] = (_Float16)fmaf((float)qv, scale, -nrm);
        }
        v8h* dst = (v8h*)(w + (size_t)g * 32);
        dst[0] = out[0]; dst[1] = out[1]; dst[2] = out[2]; dst[3] = out[3];
    } else {
        size_t i = ((size_t)(bid - 2048) * 256 + threadIdx.x) * 8;
        float4 a = *(const float4*)(x + i);
        float4 b = *(const float4*)(x + i + 4);
        v8h r;
        r[0] = (_Float16)a.x; r[1] = (_Float16)a.y; r[2] = (_Float16)a.z; r[3] = (_Float16)a.w;
        r[4] = (_Float16)b.x; r[5] = (_Float16)b.y; r[6] = (_Float16)b.z; r[7] = (_Float16)b.w;
        *(v8h*)(xo + i) = r;
    }
}

// ---------------- Kernel 2: GEMM C[M,N] = A[M,K] * B[N,K]^T + bias ----------------
// 256x256 tile, BK=32, 1024 threads (16 waves in 4x4), wave does 64x64 = 4x4 tiles of
// 16x16x32 MFMA. Halves staged bytes/FLOP vs 128x128 (R4 showed stall-dominated staging:
// only ~12 B/cyc/CU effective). __launch_bounds__(1024) caps regs at 128 -> 4 waves/SIMD.
// Double-buffered LDS (2 x 32 KB), one barrier per K-tile, compile-time buffer indices.
// Raster order: pn = pid & 15, XCD = pid % 8 -> per-XCD B working set = 2 tiles = 4 MB.
__global__ void __launch_bounds__(1024)
gemm_kernel(const _Float16* __restrict__ A,   // [M_ROWS][IN_F]
            const _Float16* __restrict__ B,   // [OUT_F][IN_F]
            const float* __restrict__ bias,   // [OUT_F]
            float* __restrict__ C) {          // [M_ROWS][OUT_F]
    __shared__ __align__(16) _Float16 As0[4 * BM * 8];  // 16 KB each
    __shared__ __align__(16) _Float16 As1[4 * BM * 8];
    __shared__ __align__(16) _Float16 Bs0[4 * BN * 8];
    __shared__ __align__(16) _Float16 Bs1[4 * BN * 8];

    const int GRID_N = OUT_F / BN;   // 16
    int pid = blockIdx.x;
    int pm = pid >> 4;               // 32 values
    int pn = pid & (GRID_N - 1);

    const int m0 = pm * BM, n0 = pn * BN;

    int t = threadIdx.x;             // [0, 1024)
    int lane = t & 63, wid = t >> 6; // 16 waves
    int wm = wid >> 2, wn = wid & 3; // 4x4 wave grid, each 64x64

    // staging: 1024 slots of 16B per matrix per tile; slot s -> kb = s>>8, row = s&255
    int srow = t & 255, skb = t >> 8;
    const _Float16* Ag = A + (size_t)(m0 + srow) * IN_F + skb * 8;
    const _Float16* Bg = B + (size_t)(n0 + srow) * IN_F + skb * 8;

    v4f acc[4][4] = {};
    const int quad = lane >> 4, lr = lane & 15;

    // LDS fragment read bases (halves): row (wm*64 + i*16 + lr), k-block quad
    const int aoff = (quad * BM + wm * 64 + lr) * 8;
    const int boff = (quad * BN + wn * 64 + lr) * 8;
    const int soff = t * 8;   // staging write offset (halves)

#define STAGE(Abuf, Bbuf, k0)                                                     \
    do {                                                                          \
        __builtin_amdgcn_global_load_lds(                                         \
            (const __attribute__((address_space(1))) void*)(Ag + (k0)),           \
            (__attribute__((address_space(3))) void*)(&Abuf[soff]), 16, 0, 0);    \
        __builtin_amdgcn_global_load_lds(                                         \
            (const __attribute__((address_space(1))) void*)(Bg + (k0)),           \
            (__attribute__((address_space(3))) void*)(&Bbuf[soff]), 16, 0, 0);    \
    } while (0)

#define COMPUTE(Abuf, Bbuf)                                                       \
    do {                                                                          \
        v8h a[4], b[4];                                                           \
        _Pragma("unroll")                                                         \
        for (int i = 0; i < 4; ++i)                                               \
            a[i] = *(const v8h*)&Abuf[aoff + i * 128];  /* i*16 rows * 8 */       \
        _Pragma("unroll")                                                         \
        for (int j = 0; j < 4; ++j)                                               \
            b[j] = *(const v8h*)&Bbuf[boff + j * 128];                            \
        _Pragma("unroll")                                                         \
        for (int i = 0; i < 4; ++i)                                               \
            _Pragma("unroll")                                                     \
            for (int j = 0; j < 4; ++j)                                           \
                acc[i][j] = __builtin_amdgcn_mfma_f32_16x16x32_f16(a[i], b[j],    \
                                                                    acc[i][j], 0, 0, 0); \
    } while (0)

    const int NT = IN_F / BK;   // 128 K-tiles (even)
    STAGE(As0, Bs0, 0);

    for (int kt = 0; kt < NT; kt += 2) {
        __syncthreads();                                   // drains buf0 loads
        STAGE(As1, Bs1, (kt + 1) * BK);
        COMPUTE(As0, Bs0);
        __syncthreads();                                   // drains buf1 loads
        if (kt + 2 < NT) STAGE(As0, Bs0, (kt + 2) * BK);
        COMPUTE(As1, Bs1);
    }
#undef STAGE
#undef COMPUTE

    // Epilogue: C/D layout col = lane&15, row = quad*4 + reg
#pragma unroll
    for (int j = 0; j < 4; ++j) {
        int n = n0 + wn * 64 + j * 16 + lr;
        float bf = bias[n];
#pragma unroll
        for (int i = 0; i < 4; ++i) {
            int mrow = m0 + wm * 64 + i * 16 + quad * 4;
#pragma unroll
            for (int rr = 0; rr < 4; ++rr)
                C[(size_t)(mrow + rr) * OUT_F + n] = acc[i][j][rr] + bf;
        }
    }
}

extern "C" void kernel_launch(void* const* d_in, const int* in_sizes, int n_in,
                              void* d_out, int out_size, void* d_ws, size_t ws_size,
                              hipStream_t stream) {
    (void)in_sizes; (void)n_in; (void)out_size; (void)ws_size;
    const float* x    = (const float*)d_in[0];
    const int*   wq   = (const int*)d_in[1];     // [524288][12] bytes, widened to int32
    const float* wnrm = (const float*)d_in[2];   // [524288]  (f16 widened to f32)
    const float* bias = (const float*)d_in[3];   // [4096]    (f16 widened to f32)
    float* out = (float*)d_out;

    _Float16* w16 = (_Float16*)d_ws;                                     // 32 MB
    _Float16* x16 = (_Float16*)((char*)d_ws + (size_t)OUT_F * IN_F * 2); // 64 MB

    prep_kernel<<<2048 + 16384, 256, 0, stream>>>(wq, wnrm, w16, x, x16);

    int grid = (M_ROWS / BM) * (OUT_F / BN);   // 512
    gemm_kernel<<<grid, 1024, 0, stream>>>(x16, w16, bias, out);
}